// Round 1
// baseline (7622.381 us; speedup 1.0000x reference)
//
#include <hip/hip_runtime.h>
#include <math.h>

#define S_LEN 256
#define BATCH 64
#define NIN   1024
#define NH    2048

typedef short s16x8 __attribute__((ext_vector_type(8)));
typedef float f32x4 __attribute__((ext_vector_type(4)));
typedef unsigned short u16x4 __attribute__((ext_vector_type(4)));

__device__ inline unsigned short f2bf(float f){
  unsigned int u = __float_as_uint(f);
  u += 0x7fffu + ((u >> 16) & 1u);      // round-to-nearest-even
  return (unsigned short)(u >> 16);
}

// cast n4*4 floats -> bf16 (vectorized float4 in, 8B out)
__global__ void k_cast_bf16(const float* __restrict__ in,
                            unsigned short* __restrict__ out, int n4){
  int i = blockIdx.x * blockDim.x + threadIdx.x;
  if (i >= n4) return;
  float4 v = ((const float4*)in)[i];
  u16x4 o;
  o.x = f2bf(v.x); o.y = f2bf(v.y); o.z = f2bf(v.z); o.w = f2bf(v.w);
  ((u16x4*)out)[i] = o;
}

// out[n][k] = bf16(in[k][n]);  K,N multiples of 32
__global__ void k_transpose_bf16(const float* __restrict__ in,
                                 unsigned short* __restrict__ out, int K, int N){
  __shared__ unsigned short tile[32][33];
  int n0 = blockIdx.x * 32, k0 = blockIdx.y * 32;
  int tx = threadIdx.x, ty = threadIdx.y;   // 32 x 8
  #pragma unroll
  for (int i = 0; i < 4; ++i)
    tile[ty + i*8][tx] = f2bf(in[(size_t)(k0 + ty + i*8) * N + n0 + tx]);
  __syncthreads();
  #pragma unroll
  for (int i = 0; i < 4; ++i)
    out[(size_t)(n0 + ty + i*8) * K + k0 + tx] = tile[tx][ty + i*8];
}

// base = x @ Wx + bx + bh  (fp32 into d_out), MFMA 16x16x32 bf16
// block: 256 thr = 4 waves; tile 64(m) x 64(n); grid (NH/64, M/64)
__global__ __launch_bounds__(256) void k_xproj(
    const unsigned short* __restrict__ xbf,   // [16384][1024] bf16
    const unsigned short* __restrict__ wxt,   // [2048][1024]  bf16 (Wx^T)
    const float* __restrict__ bx,
    const float* __restrict__ bh,
    float* __restrict__ out)                  // [16384][2048] fp32
{
  int wave = threadIdx.x >> 6, lane = threadIdx.x & 63;
  int q = lane >> 4, r = lane & 15;
  int m0 = blockIdx.y * 64 + wave * 16;
  int n0 = blockIdx.x * 64;

  const unsigned short* arow = xbf + (size_t)(m0 + r) * NIN + q * 8;
  const unsigned short* brow = wxt + (size_t)(n0 + r) * NIN + q * 8;

  f32x4 acc[4] = {};
  #pragma unroll 2
  for (int kk = 0; kk < NIN; kk += 32){
    s16x8 a = *(const s16x8*)(arow + kk);
    #pragma unroll
    for (int j = 0; j < 4; ++j){
      s16x8 b = *(const s16x8*)(brow + (size_t)j * 16 * NIN + kk);
      acc[j] = __builtin_amdgcn_mfma_f32_16x16x32_bf16(a, b, acc[j], 0, 0, 0);
    }
  }
  #pragma unroll
  for (int j = 0; j < 4; ++j){
    int col = n0 + j * 16 + r;
    float bias = bx[col] + bh[col];
    #pragma unroll
    for (int i = 0; i < 4; ++i){
      int row = m0 + q * 4 + i;
      out[(size_t)row * NH + col] = acc[j][i] + bias;
    }
  }
}

// one recurrence step: pre = base(d_out) + h @ Wh ; h' = tanh(pre)
// writes h' fp32 back into d_out (final output) and bf16 into hn.
// block: 256 thr = 4 waves (rows), tile 64(m) x 32(n); grid NH/32 = 64
__global__ __launch_bounds__(256) void k_scan(
    const unsigned short* __restrict__ hc,   // [64][2048] bf16
    unsigned short* __restrict__ hn,         // [64][2048] bf16
    const unsigned short* __restrict__ wht,  // [2048][2048] bf16 (Wh^T)
    float* __restrict__ outT)                // [64][2048] fp32 (base -> tanh)
{
  int wave = threadIdx.x >> 6, lane = threadIdx.x & 63;
  int q = lane >> 4, r = lane & 15;
  int m0 = wave * 16;
  int n0 = blockIdx.x * 32;

  const unsigned short* arow = hc  + (size_t)(m0 + r) * NH + q * 8;
  const unsigned short* brow = wht + (size_t)(n0 + r) * NH + q * 8;

  f32x4 acc[2] = {};
  #pragma unroll 4
  for (int kk = 0; kk < NH; kk += 32){
    s16x8 a = *(const s16x8*)(arow + kk);
    #pragma unroll
    for (int j = 0; j < 2; ++j){
      s16x8 b = *(const s16x8*)(brow + (size_t)j * 16 * NH + kk);
      acc[j] = __builtin_amdgcn_mfma_f32_16x16x32_bf16(a, b, acc[j], 0, 0, 0);
    }
  }
  #pragma unroll
  for (int j = 0; j < 2; ++j){
    int col = n0 + j * 16 + r;
    #pragma unroll
    for (int i = 0; i < 4; ++i){
      int row = m0 + q * 4 + i;
      size_t idx = (size_t)row * NH + col;
      float pre = acc[j][i] + outT[idx];
      float tv = tanhf(pre);
      outT[idx] = tv;
      hn[idx] = f2bf(tv);
    }
  }
}

extern "C" void kernel_launch(void* const* d_in, const int* in_sizes, int n_in,
                              void* d_out, int out_size, void* d_ws, size_t ws_size,
                              hipStream_t stream){
  const float* x  = (const float*)d_in[0];
  const float* h0 = (const float*)d_in[1];
  const float* Wx = (const float*)d_in[2];
  const float* bx = (const float*)d_in[3];
  const float* Wh = (const float*)d_in[4];
  const float* bh = (const float*)d_in[5];
  float* out = (float*)d_out;

  char* ws = (char*)d_ws;
  unsigned short* xbf  = (unsigned short*)(ws);                               // 33,554,432 B
  unsigned short* wxt  = (unsigned short*)(ws + 33554432);                    //  4,194,304 B
  unsigned short* wht  = (unsigned short*)(ws + 33554432 + 4194304);          //  8,388,608 B
  unsigned short* hbuf = (unsigned short*)(ws + 33554432 + 4194304 + 8388608);//    524,288 B

  // 1) casts
  k_cast_bf16<<<dim3(16384), 256, 0, stream>>>(x,  xbf,  4194304); // 16.7M elems
  k_cast_bf16<<<dim3(128),   256, 0, stream>>>(h0, hbuf, 32768);   // 131K elems
  // 2) weight transposes to [n][k] bf16
  k_transpose_bf16<<<dim3(NH/32, NIN/32), dim3(32, 8), 0, stream>>>(Wx, wxt, NIN, NH);
  k_transpose_bf16<<<dim3(NH/32, NH/32),  dim3(32, 8), 0, stream>>>(Wh, wht, NH, NH);
  // 3) base = x@Wx + bx + bh  -> d_out
  k_xproj<<<dim3(NH/64, (S_LEN*BATCH)/64), 256, 0, stream>>>(xbf, wxt, bx, bh, out);
  // 4) sequential scan, stream-ordered (implicit inter-step barrier)
  for (int t = 0; t < S_LEN; ++t){
    const unsigned short* hc = hbuf + (size_t)(t & 1) * BATCH * NH;
    unsigned short* hnext    = hbuf + (size_t)((t + 1) & 1) * BATCH * NH;
    k_scan<<<dim3(NH/32), 256, 0, stream>>>(hc, hnext, wht, out + (size_t)t * BATCH * NH);
  }
  // 5) hn = outputs[255]
  hipMemcpyAsync(out + (size_t)S_LEN * BATCH * NH,
                 out + (size_t)(S_LEN - 1) * BATCH * NH,
                 sizeof(float) * (size_t)BATCH * NH,
                 hipMemcpyDeviceToDevice, stream);
}

// Round 2
// 5622.657 us; speedup vs baseline: 1.3557x; 1.3557x over previous
//
#include <hip/hip_runtime.h>
#include <hip/hip_cooperative_groups.h>
#include <math.h>

namespace cg = cooperative_groups;

#define S_LEN 256
#define BATCH 64
#define NIN   1024
#define NH    2048
#define SCAN_BLOCKS 64   // 32 cols each; 4 waves/block split K 4x512

typedef short s16x8 __attribute__((ext_vector_type(8)));
typedef float f32x4 __attribute__((ext_vector_type(4)));
typedef unsigned short u16x4 __attribute__((ext_vector_type(4)));

__device__ inline unsigned short f2bf(float f){
  unsigned int u = __float_as_uint(f);
  u += 0x7fffu + ((u >> 16) & 1u);      // round-to-nearest-even
  return (unsigned short)(u >> 16);
}

__global__ void k_cast_bf16(const float* __restrict__ in,
                            unsigned short* __restrict__ out, int n4){
  int i = blockIdx.x * blockDim.x + threadIdx.x;
  if (i >= n4) return;
  float4 v = ((const float4*)in)[i];
  u16x4 o;
  o.x = f2bf(v.x); o.y = f2bf(v.y); o.z = f2bf(v.z); o.w = f2bf(v.w);
  ((u16x4*)out)[i] = o;
}

// out[n][k] = bf16(in[k][n]);  K,N multiples of 32
__global__ void k_transpose_bf16(const float* __restrict__ in,
                                 unsigned short* __restrict__ out, int K, int N){
  __shared__ unsigned short tile[32][33];
  int n0 = blockIdx.x * 32, k0 = blockIdx.y * 32;
  int tx = threadIdx.x, ty = threadIdx.y;   // 32 x 8
  #pragma unroll
  for (int i = 0; i < 4; ++i)
    tile[ty + i*8][tx] = f2bf(in[(size_t)(k0 + ty + i*8) * N + n0 + tx]);
  __syncthreads();
  #pragma unroll
  for (int i = 0; i < 4; ++i)
    out[(size_t)(n0 + ty + i*8) * K + k0 + tx] = tile[tx][ty + i*8];
}

// base = x @ Wx + bx + bh  (fp32 into d_out)
__global__ __launch_bounds__(256) void k_xproj(
    const unsigned short* __restrict__ xbf,   // [16384][1024] bf16
    const unsigned short* __restrict__ wxt,   // [2048][1024]  bf16 (Wx^T)
    const float* __restrict__ bx,
    const float* __restrict__ bh,
    float* __restrict__ out)                  // [16384][2048] fp32
{
  int wave = threadIdx.x >> 6, lane = threadIdx.x & 63;
  int q = lane >> 4, r = lane & 15;
  int m0 = blockIdx.y * 64 + wave * 16;
  int n0 = blockIdx.x * 64;

  const unsigned short* arow = xbf + (size_t)(m0 + r) * NIN + q * 8;
  const unsigned short* brow = wxt + (size_t)(n0 + r) * NIN + q * 8;

  f32x4 acc[4] = {};
  #pragma unroll 2
  for (int kk = 0; kk < NIN; kk += 32){
    s16x8 a = *(const s16x8*)(arow + kk);
    #pragma unroll
    for (int j = 0; j < 4; ++j){
      s16x8 b = *(const s16x8*)(brow + (size_t)j * 16 * NIN + kk);
      acc[j] = __builtin_amdgcn_mfma_f32_16x16x32_bf16(a, b, acc[j], 0, 0, 0);
    }
  }
  #pragma unroll
  for (int j = 0; j < 4; ++j){
    int col = n0 + j * 16 + r;
    float bias = bx[col] + bh[col];
    #pragma unroll
    for (int i = 0; i < 4; ++i){
      int row = m0 + q * 4 + i;
      out[(size_t)row * NH + col] = acc[j][i] + bias;
    }
  }
}

// Persistent weight-stationary scan: all 256 steps in one cooperative launch.
// 64 blocks x 256 thr. Block b owns cols [b*32, b*32+32). Waves split K 4x512,
// each wave holds its Wh^T slice (32 cols x 512 k) in 128 VGPRs.
__global__ __launch_bounds__(256, 1) void k_scan_persist(
    unsigned short* __restrict__ hbuf,      // 2 x [64][2048] bf16 ping-pong (slot0 = h0)
    const unsigned short* __restrict__ wht, // [2048][2048] bf16 (Wh^T)
    float* __restrict__ out)                // [256][64][2048] fp32 (base in, tanh out)
{
  cg::grid_group grid = cg::this_grid();
  __shared__ float red[4][64 * 32];

  const int wave = threadIdx.x >> 6, lane = threadIdx.x & 63;
  const int q = lane >> 4, r = lane & 15;
  const int n0 = blockIdx.x * 32;
  const int kbase = wave * 512;

  // ---- preload Wh^T slice into registers (once) ----
  s16x8 breg[2][16];
  #pragma unroll
  for (int kk = 0; kk < 16; ++kk)
    #pragma unroll
    for (int j = 0; j < 2; ++j)
      breg[j][kk] = *(const s16x8*)(wht + (size_t)(n0 + j*16 + r) * NH + kbase + kk*32 + q*8);

  const int tid = threadIdx.x;
  const int row = tid >> 2, c0 = (tid & 3) * 8;

  for (int t = 0; t < S_LEN; ++t){
    const unsigned short* hc = hbuf + (size_t)(t & 1) * BATCH * NH;
    unsigned short* hn       = hbuf + (size_t)((t + 1) & 1) * BATCH * NH;
    float* outT = out + (size_t)t * BATCH * NH;

    // ---- partial GEMM over this wave's k-quarter ----
    f32x4 acc[4][2] = {};
    #pragma unroll
    for (int kk = 0; kk < 16; ++kk){
      s16x8 a[4];
      #pragma unroll
      for (int m = 0; m < 4; ++m)
        a[m] = *(const s16x8*)(hc + (size_t)(m*16 + r) * NH + kbase + kk*32 + q*8);
      #pragma unroll
      for (int m = 0; m < 4; ++m)
        #pragma unroll
        for (int j = 0; j < 2; ++j)
          acc[m][j] = __builtin_amdgcn_mfma_f32_16x16x32_bf16(a[m], breg[j][kk], acc[m][j], 0, 0, 0);
    }

    // ---- k-reduce across 4 waves via LDS ----
    #pragma unroll
    for (int m = 0; m < 4; ++m)
      #pragma unroll
      for (int j = 0; j < 2; ++j)
        #pragma unroll
        for (int i = 0; i < 4; ++i)
          red[wave][(m*16 + q*4 + i) * 32 + j*16 + r] = acc[m][j][i];
    __syncthreads();

    // ---- sum partials + base, tanh, store (256 thr x 8 elems) ----
    #pragma unroll
    for (int e = 0; e < 2; ++e){
      int loff = row * 32 + c0 + e * 4;
      f32x4 s = *(const f32x4*)&red[0][loff];
      #pragma unroll
      for (int w2 = 1; w2 < 4; ++w2)
        s += *(const f32x4*)&red[w2][loff];
      size_t gidx = (size_t)row * NH + n0 + c0 + e * 4;
      f32x4 base = *(const f32x4*)(outT + gidx);
      f32x4 tv;
      u16x4 hb;
      #pragma unroll
      for (int i = 0; i < 4; ++i){
        tv[i] = tanhf(base[i] + s[i]);
        ((unsigned short*)&hb)[i] = f2bf(tv[i]);
      }
      *(f32x4*)(outT + gidx) = tv;
      *(u16x4*)(hn + gidx) = hb;
    }

    grid.sync();   // h(t+1) visible device-wide; also guards LDS reuse
  }
}

extern "C" void kernel_launch(void* const* d_in, const int* in_sizes, int n_in,
                              void* d_out, int out_size, void* d_ws, size_t ws_size,
                              hipStream_t stream){
  const float* x  = (const float*)d_in[0];
  const float* h0 = (const float*)d_in[1];
  const float* Wx = (const float*)d_in[2];
  const float* bx = (const float*)d_in[3];
  const float* Wh = (const float*)d_in[4];
  const float* bh = (const float*)d_in[5];
  float* out = (float*)d_out;

  char* ws = (char*)d_ws;
  unsigned short* xbf  = (unsigned short*)(ws);                               // 33,554,432 B
  unsigned short* wxt  = (unsigned short*)(ws + 33554432);                    //  4,194,304 B
  unsigned short* wht  = (unsigned short*)(ws + 33554432 + 4194304);          //  8,388,608 B
  unsigned short* hbuf = (unsigned short*)(ws + 33554432 + 4194304 + 8388608);//    524,288 B

  // 1) casts
  k_cast_bf16<<<dim3(16384), 256, 0, stream>>>(x,  xbf,  4194304);
  k_cast_bf16<<<dim3(128),   256, 0, stream>>>(h0, hbuf, 32768);
  // 2) weight transposes to [n][k] bf16
  k_transpose_bf16<<<dim3(NH/32, NIN/32), dim3(32, 8), 0, stream>>>(Wx, wxt, NIN, NH);
  k_transpose_bf16<<<dim3(NH/32, NH/32),  dim3(32, 8), 0, stream>>>(Wh, wht, NH, NH);
  // 3) base = x@Wx + bx + bh -> d_out
  k_xproj<<<dim3(NH/64, (S_LEN*BATCH)/64), 256, 0, stream>>>(xbf, wxt, bx, bh, out);
  // 4) persistent cooperative scan (all 256 steps, weight-stationary)
  {
    void* args[] = { (void*)&hbuf, (void*)&wht, (void*)&out };
    hipLaunchCooperativeKernel((const void*)k_scan_persist,
                               dim3(SCAN_BLOCKS), dim3(256), args, 0, stream);
  }
  // 5) hn = outputs[255]
  hipMemcpyAsync(out + (size_t)S_LEN * BATCH * NH,
                 out + (size_t)(S_LEN - 1) * BATCH * NH,
                 sizeof(float) * (size_t)BATCH * NH,
                 hipMemcpyDeviceToDevice, stream);
}

// Round 3
// 5520.578 us; speedup vs baseline: 1.3807x; 1.0185x over previous
//
#include <hip/hip_runtime.h>
#include <math.h>

#define S_LEN 256
#define BATCH 64
#define NIN   1024
#define NH    2048
#define SCAN_BLOCKS  64    // 32 cols each
#define SCAN_THREADS 512   // 8 waves, K-split 8x256

typedef short s16x8 __attribute__((ext_vector_type(8)));
typedef float f32x4 __attribute__((ext_vector_type(4)));
typedef unsigned short u16x4 __attribute__((ext_vector_type(4)));

__device__ inline unsigned short f2bf(float f){
  unsigned int u = __float_as_uint(f);
  u += 0x7fffu + ((u >> 16) & 1u);      // round-to-nearest-even
  return (unsigned short)(u >> 16);
}

__global__ void k_cast_bf16(const float* __restrict__ in,
                            unsigned short* __restrict__ out, int n4){
  int i = blockIdx.x * blockDim.x + threadIdx.x;
  if (i >= n4) return;
  float4 v = ((const float4*)in)[i];
  u16x4 o;
  o.x = f2bf(v.x); o.y = f2bf(v.y); o.z = f2bf(v.z); o.w = f2bf(v.w);
  ((u16x4*)out)[i] = o;
}

// out[n][k] = bf16(in[k][n]);  K,N multiples of 32
__global__ void k_transpose_bf16(const float* __restrict__ in,
                                 unsigned short* __restrict__ out, int K, int N){
  __shared__ unsigned short tile[32][33];
  int n0 = blockIdx.x * 32, k0 = blockIdx.y * 32;
  int tx = threadIdx.x, ty = threadIdx.y;   // 32 x 8
  #pragma unroll
  for (int i = 0; i < 4; ++i)
    tile[ty + i*8][tx] = f2bf(in[(size_t)(k0 + ty + i*8) * N + n0 + tx]);
  __syncthreads();
  #pragma unroll
  for (int i = 0; i < 4; ++i)
    out[(size_t)(n0 + ty + i*8) * K + k0 + tx] = tile[tx][ty + i*8];
}

// base = x @ Wx + bx + bh  (fp32 into d_out)
__global__ __launch_bounds__(256) void k_xproj(
    const unsigned short* __restrict__ xbf,   // [16384][1024] bf16
    const unsigned short* __restrict__ wxt,   // [2048][1024]  bf16 (Wx^T)
    const float* __restrict__ bx,
    const float* __restrict__ bh,
    float* __restrict__ out)                  // [16384][2048] fp32
{
  int wave = threadIdx.x >> 6, lane = threadIdx.x & 63;
  int q = lane >> 4, r = lane & 15;
  int m0 = blockIdx.y * 64 + wave * 16;
  int n0 = blockIdx.x * 64;

  const unsigned short* arow = xbf + (size_t)(m0 + r) * NIN + q * 8;
  const unsigned short* brow = wxt + (size_t)(n0 + r) * NIN + q * 8;

  f32x4 acc[4] = {};
  #pragma unroll 2
  for (int kk = 0; kk < NIN; kk += 32){
    s16x8 a = *(const s16x8*)(arow + kk);
    #pragma unroll
    for (int j = 0; j < 4; ++j){
      s16x8 b = *(const s16x8*)(brow + (size_t)j * 16 * NIN + kk);
      acc[j] = __builtin_amdgcn_mfma_f32_16x16x32_bf16(a, b, acc[j], 0, 0, 0);
    }
  }
  #pragma unroll
  for (int j = 0; j < 4; ++j){
    int col = n0 + j * 16 + r;
    float bias = bx[col] + bh[col];
    #pragma unroll
    for (int i = 0; i < 4; ++i){
      int row = m0 + q * 4 + i;
      out[(size_t)row * NH + col] = acc[j][i] + bias;
    }
  }
}

// Persistent weight-stationary scan, custom lean barrier.
// 64 blocks x 512 thr (8 waves). Block owns 32 cols; waves K-split 8x256.
// Weight slice per wave: 16 frags = 64 VGPRs (register-resident).
// All scan-cycle global stores are device-scope (sc0 sc1) => L2 never dirty
// => release/acquire fences are cheap; h loads stay L2-cached within a step.
__global__ __launch_bounds__(SCAN_THREADS, 2) void k_scan_persist(
    unsigned short* __restrict__ hbuf,      // 2 x [64][2048] bf16 ping-pong (slot0 = h0)
    const unsigned short* __restrict__ wht, // [2048][2048] bf16 (Wh^T)
    float* __restrict__ out,                // [256][64][2048] fp32 (base in, tanh out)
    unsigned int* __restrict__ bar)         // zeroed counter
{
  __shared__ float red[4][BATCH][32];

  const int tid = threadIdx.x;
  const int wave = tid >> 6, lane = tid & 63;
  const int q = lane >> 4, r = lane & 15;
  const int n0 = blockIdx.x * 32;
  const int kbase = wave * 256;

  // ---- preload Wh^T slice into registers (once): 2 n-tiles x 8 k-tiles ----
  s16x8 breg[2][8];
  #pragma unroll
  for (int kk = 0; kk < 8; ++kk)
    #pragma unroll
    for (int j = 0; j < 2; ++j)
      breg[j][kk] = *(const s16x8*)(wht + (size_t)(n0 + j*16 + r) * NH + kbase + kk*32 + q*8);

  const int crow = tid >> 3;        // 0..63  (epilogue mapping)
  const int ccol = (tid & 7) * 4;   // 0..28

  for (int t = 0; t < S_LEN; ++t){
    const unsigned short* hc = hbuf + (size_t)(t & 1) * BATCH * NH;
    unsigned short* hn       = hbuf + (size_t)((t + 1) & 1) * BATCH * NH;
    float* outT = out + (size_t)t * BATCH * NH;

    // make previous step's device-scope h stores visible (invalidate L2/L1)
    __builtin_amdgcn_fence(__ATOMIC_ACQUIRE, "agent");

    // ---- partial GEMM over this wave's k-range (K=256) ----
    f32x4 acc[4][2] = {};
    #pragma unroll 2
    for (int kk = 0; kk < 8; ++kk){
      s16x8 a[4];
      #pragma unroll
      for (int m = 0; m < 4; ++m)
        a[m] = *(const s16x8*)(hc + (size_t)(m*16 + r) * NH + kbase + kk*32 + q*8);
      #pragma unroll
      for (int m = 0; m < 4; ++m)
        #pragma unroll
        for (int j = 0; j < 2; ++j)
          acc[m][j] = __builtin_amdgcn_mfma_f32_16x16x32_bf16(a[m], breg[j][kk], acc[m][j], 0, 0, 0);
    }

    // ---- two-pass cross-wave K-reduce in LDS (8 -> 4 partials) ----
    if (wave >= 4){
      #pragma unroll
      for (int m = 0; m < 4; ++m)
        #pragma unroll
        for (int j = 0; j < 2; ++j)
          #pragma unroll
          for (int i = 0; i < 4; ++i)
            red[wave-4][m*16 + q*4 + i][j*16 + r] = acc[m][j][i];
    }
    __syncthreads();
    if (wave < 4){
      #pragma unroll
      for (int m = 0; m < 4; ++m)
        #pragma unroll
        for (int j = 0; j < 2; ++j)
          #pragma unroll
          for (int i = 0; i < 4; ++i)
            red[wave][m*16 + q*4 + i][j*16 + r] += acc[m][j][i];
    }
    __syncthreads();

    // ---- epilogue: all 512 threads, 4 elems each ----
    {
      f32x4 s = *(const f32x4*)&red[0][crow][ccol];
      #pragma unroll
      for (int w = 1; w < 4; ++w)
        s += *(const f32x4*)&red[w][crow][ccol];
      size_t g = (size_t)crow * NH + n0 + ccol;
      f32x4 base = *(const f32x4*)(outT + g);
      float tv[4];
      #pragma unroll
      for (int i = 0; i < 4; ++i) tv[i] = tanhf(base[i] + s[i]);

      union { float f[2]; unsigned long long u; } p0, p1;
      p0.f[0] = tv[0]; p0.f[1] = tv[1];
      p1.f[0] = tv[2]; p1.f[1] = tv[3];
      __hip_atomic_store((unsigned long long*)(outT + g),     p0.u,
                         __ATOMIC_RELAXED, __HIP_MEMORY_SCOPE_AGENT);
      __hip_atomic_store((unsigned long long*)(outT + g) + 1, p1.u,
                         __ATOMIC_RELAXED, __HIP_MEMORY_SCOPE_AGENT);
      union { unsigned short h[4]; unsigned long long u; } ph;
      #pragma unroll
      for (int i = 0; i < 4; ++i) ph.h[i] = f2bf(tv[i]);
      __hip_atomic_store((unsigned long long*)(hn + g), ph.u,
                         __ATOMIC_RELAXED, __HIP_MEMORY_SCOPE_AGENT);
    }

    // ---- lean device barrier ----
    __syncthreads();   // drains each wave's vmcnt => sc1 stores at coherence pt
    if (tid == 0){
      __hip_atomic_fetch_add(bar, 1u, __ATOMIC_RELEASE, __HIP_MEMORY_SCOPE_AGENT);
      unsigned int target = (unsigned int)(t + 1) * SCAN_BLOCKS;
      while (__hip_atomic_load(bar, __ATOMIC_RELAXED, __HIP_MEMORY_SCOPE_AGENT) < target)
        __builtin_amdgcn_s_sleep(2);
    }
    __syncthreads();
  }
}

extern "C" void kernel_launch(void* const* d_in, const int* in_sizes, int n_in,
                              void* d_out, int out_size, void* d_ws, size_t ws_size,
                              hipStream_t stream){
  const float* x  = (const float*)d_in[0];
  const float* h0 = (const float*)d_in[1];
  const float* Wx = (const float*)d_in[2];
  const float* bx = (const float*)d_in[3];
  const float* Wh = (const float*)d_in[4];
  const float* bh = (const float*)d_in[5];
  float* out = (float*)d_out;

  char* ws = (char*)d_ws;
  unsigned short* xbf  = (unsigned short*)(ws);                               // 33,554,432 B
  unsigned short* wxt  = (unsigned short*)(ws + 33554432);                    //  4,194,304 B
  unsigned short* wht  = (unsigned short*)(ws + 33554432 + 4194304);          //  8,388,608 B
  unsigned short* hbuf = (unsigned short*)(ws + 33554432 + 4194304 + 8388608);//    524,288 B
  // barrier counter aliases xbf[0..2) — xbf is dead after k_xproj completes
  unsigned int* bar = (unsigned int*)ws;

  // 1) casts
  k_cast_bf16<<<dim3(16384), 256, 0, stream>>>(x,  xbf,  4194304);
  k_cast_bf16<<<dim3(128),   256, 0, stream>>>(h0, hbuf, 32768);
  // 2) weight transposes to [n][k] bf16
  k_transpose_bf16<<<dim3(NH/32, NIN/32), dim3(32, 8), 0, stream>>>(Wx, wxt, NIN, NH);
  k_transpose_bf16<<<dim3(NH/32, NH/32),  dim3(32, 8), 0, stream>>>(Wh, wht, NH, NH);
  // 3) base = x@Wx + bx + bh -> d_out
  k_xproj<<<dim3(NH/64, (S_LEN*BATCH)/64), 256, 0, stream>>>(xbf, wxt, bx, bh, out);
  // 4) zero barrier counter (xbf dead now), then persistent scan
  hipMemsetAsync(bar, 0, sizeof(unsigned int), stream);
  {
    void* args[] = { (void*)&hbuf, (void*)&wht, (void*)&out, (void*)&bar };
    hipLaunchCooperativeKernel((const void*)k_scan_persist,
                               dim3(SCAN_BLOCKS), dim3(SCAN_THREADS), args, 0, stream);
  }
  // 5) hn = outputs[255]
  hipMemcpyAsync(out + (size_t)S_LEN * BATCH * NH,
                 out + (size_t)(S_LEN - 1) * BATCH * NH,
                 sizeof(float) * (size_t)BATCH * NH,
                 hipMemcpyDeviceToDevice, stream);
}